// Round 13
// baseline (314.006 us; speedup 1.0000x reference)
//
#include <hip/hip_runtime.h>
#include <cstdint>

// ---------------------------------------------------------------------------
// GCN pipeline (bf16 MFMA GEMMs, binned CSR build):
//  binhist -> binscan -> binscatter -> k_csr -> GEMM1(fused cast, xW*dinv)
//  -> AGGEMM (agg layer1 + WAVE-PRIVATE fused GEMM2 tail, no barriers)
//  -> AGG2 -> fused pool+head.  Graph ranges via sorted-batch boundaries.
// ---------------------------------------------------------------------------

#define BK_SHIFT 9
#define BK_NODES 512            // 1 << BK_SHIFT
#define CH 4096                 // edges per binscatter chunk
#define NODE_BITS 17            // N=100000 < 2^17
#define NODE_MASK ((1 << NODE_BITS) - 1)

typedef short bf16x8 __attribute__((ext_vector_type(8)));
typedef float f32x4 __attribute__((ext_vector_type(4)));

union bfpack {
    uint4 u;
    bf16x8 b;
};

// f32 -> bf16 round-to-nearest-even
static __device__ __forceinline__ unsigned int f2bf(float f) {
    unsigned int u = __float_as_uint(f);
    return (u + 0x7fffu + ((u >> 16) & 1u)) >> 16;
}
static __device__ __forceinline__ unsigned int packbf2(float a, float b) {
    return f2bf(a) | (f2bf(b) << 16);
}
static __device__ __forceinline__ float bf_lo(unsigned int v) {
    return __uint_as_float(v << 16);
}
static __device__ __forceinline__ float bf_hi(unsigned int v) {
    return __uint_as_float(v & 0xffff0000u);
}

// gstart/gend init + zero bucket counters
__global__ void k_init_small(int* gstart, int* gend, int G, int* bcnt, int NBK) {
    int g = blockIdx.x * blockDim.x + threadIdx.x;
    if (g < G) { gstart[g] = 0x7fffffff; gend[g] = 0; }
    if (g < NBK) bcnt[g] = 0;
}

// sorted batch -> contiguous runs; boundary threads are unique writers
__global__ void k_init_nodes(const int* __restrict__ batch,
                             int* __restrict__ gstart, int* __restrict__ gend, int N) {
    int i = blockIdx.x * blockDim.x + threadIdx.x;
    if (i >= N) return;
    int b = batch[i];
    if (i == 0 || batch[i - 1] != b) gstart[b] = i;
    if (i == N - 1 || batch[i + 1] != b) gend[b] = i + 1;
}

// ---- Pass A1: per-bucket edge counts (4-way split hist: less contention) ---
__global__ __launch_bounds__(256) void k_binhist(const int* __restrict__ dst, int E,
                                                 int* __restrict__ bcnt, int NBK) {
    __shared__ int h[4][256];
    int tid = threadIdx.x;
    int wid = tid >> 6;
#pragma unroll
    for (int w = 0; w < 4; ++w) h[w][tid & 255] = 0;
    __syncthreads();
    int base = blockIdx.x * CH;
    int nend = min(base + CH, E);
    for (int i = base + tid; i < nend; i += 256) atomicAdd(&h[wid][dst[i] >> BK_SHIFT], 1);
    __syncthreads();
    if (tid < NBK) {
        int s = h[0][tid] + h[1][tid] + h[2][tid] + h[3][tid];
        if (s) atomicAdd(&bcnt[tid], s);
    }
}

// ---- Pass A2: scan bucket counts -> bbase[NBK+1], bfill cursors ------------
__global__ __launch_bounds__(256) void k_binscan(const int* __restrict__ bcnt,
                                                 int* __restrict__ bbase,
                                                 int* __restrict__ bfill, int NBK) {
    __shared__ int sc[256];
    int tid = threadIdx.x;
    int v = (tid < NBK) ? bcnt[tid] : 0;
    sc[tid] = v;
    __syncthreads();
    for (int d = 1; d < 256; d <<= 1) {
        int t = (tid >= d) ? sc[tid - d] : 0;
        __syncthreads();
        sc[tid] += t;
        __syncthreads();
    }
    int excl = sc[tid] - v;
    if (tid < NBK) { bbase[tid] = excl; bfill[tid] = excl; }
    if (tid == 255) bbase[NBK] = sc[255];  // total = E
}

// ---- Pass A3: counting-sort each 4096-edge chunk into bucket-major order ---
__global__ __launch_bounds__(256) void k_binscatter(const int* __restrict__ src,
                                                    const int* __restrict__ dst,
                                                    const float* __restrict__ ew,
                                                    int* __restrict__ bfill,
                                                    int2* __restrict__ binned, int E) {
    __shared__ int2 stage2[CH];          // 32 KB
    __shared__ unsigned char bkt2[CH];   // 4 KB
    __shared__ int hist[256], sc[256], lofs[256], cnt2[256], gbase[256];
    int tid = threadIdx.x;
    int base = blockIdx.x * CH;
    int n = min(CH, E - base);
    hist[tid] = 0;
    cnt2[tid] = 0;
    __syncthreads();
    int2 ev[CH / 256];
    int bk[CH / 256];
#pragma unroll
    for (int j = 0; j < CH / 256; ++j) {
        int i = base + tid + j * 256;
        bk[j] = -1;
        if (i < base + n) {
            int s = src[i], d = dst[i];
            float w = ew[i];
            int b = d >> BK_SHIFT;
            ev[j] = make_int2(s | ((d & (BK_NODES - 1)) << NODE_BITS), __float_as_int(w));
            bk[j] = b;
            atomicAdd(&hist[b], 1);
        }
    }
    __syncthreads();
    int hv = hist[tid];
    sc[tid] = hv;
    __syncthreads();
    for (int d = 1; d < 256; d <<= 1) {
        int t = (tid >= d) ? sc[tid - d] : 0;
        __syncthreads();
        sc[tid] += t;
        __syncthreads();
    }
    lofs[tid] = sc[tid] - hv;
    gbase[tid] = hv ? atomicAdd(&bfill[tid], hv) : 0;
    __syncthreads();
#pragma unroll
    for (int j = 0; j < CH / 256; ++j) {
        if (bk[j] >= 0) {
            int r = atomicAdd(&cnt2[bk[j]], 1);
            int p = lofs[bk[j]] + r;
            stage2[p] = ev[j];
            bkt2[p] = (unsigned char)bk[j];
        }
    }
    __syncthreads();
    for (int i = tid; i < n; i += 256) {
        int b = bkt2[i];
        binned[gbase[b] + (i - lofs[b])] = stage2[i];
    }
}

// ---- Pass B: per-bucket local CSR + rowptr + dinv --------------------------
__global__ __launch_bounds__(256) void k_csr(const int2* __restrict__ binned,
                                             const int* __restrict__ bbase,
                                             int2* __restrict__ cvb,
                                             int* __restrict__ rowptr,
                                             float* __restrict__ dinv, int N, int E) {
    __shared__ int lh[BK_NODES];
    __shared__ float ls[BK_NODES];
    __shared__ int lofs[BK_NODES];
    __shared__ int s2[256];
    int tid = threadIdx.x;
    int b = blockIdx.x;
    int nbase = b << BK_SHIFT;
    int nend = min(nbase + BK_NODES, N);
    int ebase = bbase[b], eend = bbase[b + 1];
    for (int i = tid; i < BK_NODES; i += 256) { lh[i] = 0; ls[i] = 0.f; }
    __syncthreads();
    for (int e = ebase + tid; e < eend; e += 256) {
        int2 v = binned[e];
        int local = (v.x >> NODE_BITS) & (BK_NODES - 1);
        atomicAdd(&lh[local], 1);
        atomicAdd(&ls[local], __int_as_float(v.y));
    }
    __syncthreads();
    // exclusive scan of lh[512] via pairwise + 256-scan
    int p0 = lh[2 * tid], p1 = lh[2 * tid + 1];
    int pv = p0 + p1;
    s2[tid] = pv;
    __syncthreads();
    for (int d = 1; d < 256; d <<= 1) {
        int t = (tid >= d) ? s2[tid - d] : 0;
        __syncthreads();
        s2[tid] += t;
        __syncthreads();
    }
    int e2 = s2[tid] - pv;  // exclusive over pairs
    lofs[2 * tid] = e2;
    lofs[2 * tid + 1] = e2 + p0;
    __syncthreads();
    for (int i = nbase + tid; i < nend; i += 256) {
        int local = i - nbase;
        rowptr[i] = ebase + lofs[local];
        dinv[i] = rsqrtf(1.0f + ls[local]);
    }
    if (b == 0 && tid == 0) rowptr[N] = E;
    __syncthreads();
    for (int e = ebase + tid; e < eend; e += 256) {
        int2 v = binned[e];
        int local = (v.x >> NODE_BITS) & (BK_NODES - 1);
        int r = atomicAdd(&lofs[local], 1);
        cvb[ebase + r] = make_int2(v.x & NODE_MASK, v.y);
    }
}

// both W -> WT transposes in one launch (grid 128)
__global__ __launch_bounds__(256) void k_wtboth(const float* __restrict__ W1,
                                                const float* __restrict__ W2,
                                                unsigned short* __restrict__ WT1,
                                                unsigned short* __restrict__ WT2) {
    int idx = blockIdx.x * 256 + threadIdx.x;
    const float* W = (idx < 16384) ? W1 : W2;
    unsigned short* WT = (idx < 16384) ? WT1 : WT2;
    int i = idx & 16383;
    int n = i >> 7, k = i & 127;
    WT[i] = (unsigned short)f2bf(W[(size_t)k * 128 + n]);
}

// Layer 1: Y[M,128](bf16) = dinv[row] * (x_f32[M,128] @ W), cast fused.
__global__ __launch_bounds__(256) void k_gemm1(const float* __restrict__ X,
                                               const unsigned short* __restrict__ WT,
                                               const float* __restrict__ dinv,
                                               unsigned short* __restrict__ Y, int M) {
    int tid = threadIdx.x;
    int wid = tid >> 6, lane = tid & 63;
    int rowb = blockIdx.x * 64 + wid * 16;
    int r16 = lane & 15, kg = lane >> 4;
    int arow = min(rowb + r16, M - 1);  // clamp: garbage only affects unsaved pad rows
    const float* xr = X + (size_t)arow * 128 + kg * 8;
    bf16x8 a[4];
#pragma unroll
    for (int kc = 0; kc < 4; ++kc) {
        float4 u = *reinterpret_cast<const float4*>(xr + kc * 32);
        float4 v = *reinterpret_cast<const float4*>(xr + kc * 32 + 4);
        bfpack pk;
        pk.u = make_uint4(packbf2(u.x, u.y), packbf2(u.z, u.w),
                          packbf2(v.x, v.y), packbf2(v.z, v.w));
        a[kc] = pk.b;
    }
    float dv[4];
#pragma unroll
    for (int r = 0; r < 4; ++r) {
        int ro = rowb + kg * 4 + r;
        dv[r] = (ro < M) ? dinv[ro] : 0.f;
    }
    const bf16x8* Bp = reinterpret_cast<const bf16x8*>(WT + (size_t)r16 * 128 + kg * 8);
#pragma unroll
    for (int nt = 0; nt < 8; ++nt) {
        const bf16x8* B = Bp + (size_t)nt * 256;
        f32x4 acc = {0.f, 0.f, 0.f, 0.f};
        acc = __builtin_amdgcn_mfma_f32_16x16x32_bf16(a[0], B[0], acc, 0, 0, 0);
        acc = __builtin_amdgcn_mfma_f32_16x16x32_bf16(a[1], B[4], acc, 0, 0, 0);
        acc = __builtin_amdgcn_mfma_f32_16x16x32_bf16(a[2], B[8], acc, 0, 0, 0);
        acc = __builtin_amdgcn_mfma_f32_16x16x32_bf16(a[3], B[12], acc, 0, 0, 0);
        int colo = nt * 16 + r16;
#pragma unroll
        for (int r = 0; r < 4; ++r) {
            int ro = rowb + kg * 4 + r;
            if (ro < M) Y[(size_t)ro * 128 + colo] = (unsigned short)f2bf(acc[r] * dv[r]);
        }
    }
}

// AGG layer1 + WAVE-PRIVATE fused GEMM2 tail (no __syncthreads anywhere).
// Gather phase: 8 nodes/wave (4 slots x 2 half-wave rows).  The wave then
// stages its own 8 relu'd rows into ITS OWN LDS region (aliasing its gather
// staging buffer -- free after the gather loop; per-wave DS ops are in-order
// and the alias is protected by the dataflow dependency) and runs an
// M=8-padded-to-16 MFMA over W2 for its own rows only.
__global__ __launch_bounds__(256) void k_aggemm(const uint2* __restrict__ Hb2,
                                                const int* __restrict__ rowptr,
                                                const int2* __restrict__ cvb,
                                                const float* __restrict__ dinv,
                                                const float* __restrict__ bias,
                                                const unsigned short* __restrict__ WT2,
                                                unsigned short* __restrict__ Y, int N) {
    __shared__ int2 smbuf[4][512];  // 16 KB: per-wave 4 KB region
    int tid = threadIdx.x;
    int lane = tid & 63, wid = tid >> 6;
    int half = lane >> 5, sl = lane & 31;
    // per-wave views over the same 4 KB
    int2 (*lcv)[2][64] = reinterpret_cast<int2(*)[2][64]>(&smbuf[wid][0]);  // [4][2][64]
    uint2 (*hst)[33]   = reinterpret_cast<uint2(*)[33]>(&smbuf[wid][0]);    // [8][33]
    int n0 = (blockIdx.x * 4 + wid) * 8;
    if (n0 >= N) return;
    int rv = rowptr[min(n0 + min(lane, 8), N)];
    int rp[9];
#pragma unroll
    for (int k = 0; k < 9; ++k) rp[k] = __shfl(rv, k);
    int cnt[8];
    int nmax = 0;
#pragma unroll
    for (int k = 0; k < 8; ++k) {
        cnt[k] = rp[k + 1] - rp[k];
        nmax = max(nmax, cnt[k]);
    }
    float a[4][4];
#pragma unroll
    for (int s = 0; s < 4; ++s) {
        int ns = n0 + 2 * s + half;
        uint2 hv = (ns < N) ? Hb2[(size_t)ns * 32 + sl] : make_uint2(0u, 0u);
        a[s][0] = bf_lo(hv.x);
        a[s][1] = bf_hi(hv.x);
        a[s][2] = bf_lo(hv.y);
        a[s][3] = bf_hi(hv.y);
    }
    for (int base = 0; base < nmax; base += 64) {
#pragma unroll
        for (int s = 0; s < 4; ++s) {
#pragma unroll
            for (int h = 0; h < 2; ++h) {
                int k = 2 * s + h;
                int2 t = (base + lane < cnt[k]) ? cvb[rp[k] + base + lane]
                                                : make_int2(0, 0);
                lcv[s][h][lane] = t;
            }
        }
        int m = min(64, nmax - base);
        for (int j0 = 0; j0 < m; j0 += 8) {
#pragma unroll
            for (int jj = 0; jj < 8; ++jj) {
                int j = j0 + jj;
                if (j < m) {
                    int2 e0 = lcv[0][half][j];
                    int2 e1 = lcv[1][half][j];
                    int2 e2 = lcv[2][half][j];
                    int2 e3 = lcv[3][half][j];
                    uint2 h0 = Hb2[(size_t)e0.x * 32 + sl];
                    uint2 h1 = Hb2[(size_t)e1.x * 32 + sl];
                    uint2 h2 = Hb2[(size_t)e2.x * 32 + sl];
                    uint2 h3 = Hb2[(size_t)e3.x * 32 + sl];
                    float w0 = __int_as_float(e0.y);
                    float w1 = __int_as_float(e1.y);
                    float w2 = __int_as_float(e2.y);
                    float w3 = __int_as_float(e3.y);
                    a[0][0] = fmaf(w0, bf_lo(h0.x), a[0][0]);
                    a[0][1] = fmaf(w0, bf_hi(h0.x), a[0][1]);
                    a[0][2] = fmaf(w0, bf_lo(h0.y), a[0][2]);
                    a[0][3] = fmaf(w0, bf_hi(h0.y), a[0][3]);
                    a[1][0] = fmaf(w1, bf_lo(h1.x), a[1][0]);
                    a[1][1] = fmaf(w1, bf_hi(h1.x), a[1][1]);
                    a[1][2] = fmaf(w1, bf_lo(h1.y), a[1][2]);
                    a[1][3] = fmaf(w1, bf_hi(h1.y), a[1][3]);
                    a[2][0] = fmaf(w2, bf_lo(h2.x), a[2][0]);
                    a[2][1] = fmaf(w2, bf_hi(h2.x), a[2][1]);
                    a[2][2] = fmaf(w2, bf_lo(h2.y), a[2][2]);
                    a[2][3] = fmaf(w2, bf_hi(h2.y), a[2][3]);
                    a[3][0] = fmaf(w3, bf_lo(h3.x), a[3][0]);
                    a[3][1] = fmaf(w3, bf_hi(h3.x), a[3][1]);
                    a[3][2] = fmaf(w3, bf_lo(h3.y), a[3][2]);
                    a[3][3] = fmaf(w3, bf_hi(h3.y), a[3][3]);
                }
            }
        }
    }
    // layer-1 epilogue: bias + relu -> wave-private LDS rows (row j = node n0+j)
    float4 bv = reinterpret_cast<const float4*>(bias)[sl];
#pragma unroll
    for (int s = 0; s < 4; ++s) {
        int ns = n0 + 2 * s + half;
        uint2 o = make_uint2(0u, 0u);
        if (ns < N) {
            float d = dinv[ns];
            float o0 = fmaxf(fmaf(a[s][0], d, bv.x), 0.f);
            float o1 = fmaxf(fmaf(a[s][1], d, bv.y), 0.f);
            float o2 = fmaxf(fmaf(a[s][2], d, bv.z), 0.f);
            float o3 = fmaxf(fmaf(a[s][3], d, bv.w), 0.f);
            o = make_uint2(packbf2(o0, o1), packbf2(o2, o3));
        }
        hst[2 * s + half][sl] = o;
    }
    // ---- wave-private MFMA tail: own 8 rows (A rows 8..15 zero) x W2 ----
    int r16 = lane & 15, kg = lane >> 4;
    bf16x8 afr[4];
#pragma unroll
    for (int kc = 0; kc < 4; ++kc) {
        bfpack pk;
        pk.u = make_uint4(0u, 0u, 0u, 0u);
        if (r16 < 8) {
            uint2 lo = hst[r16][kc * 8 + kg * 2];
            uint2 hi = hst[r16][kc * 8 + kg * 2 + 1];
            pk.u = make_uint4(lo.x, lo.y, hi.x, hi.y);
        }
        afr[kc] = pk.b;
    }
    float dv[4];
#pragma unroll
    for (int r = 0; r < 4; ++r) {
        int row = kg * 4 + r;
        int ro = n0 + row;
        dv[r] = (row < 8 && ro < N) ? dinv[ro] : 0.f;
    }
    const bf16x8* Bp = reinterpret_cast<const bf16x8*>(WT2 + (size_t)r16 * 128 + kg * 8);
#pragma unroll
    for (int nt = 0; nt < 8; ++nt) {
        const bf16x8* B = Bp + (size_t)nt * 256;
        f32x4 acc = {0.f, 0.f, 0.f, 0.f};
        acc = __builtin_amdgcn_mfma_f32_16x16x32_bf16(afr[0], B[0], acc, 0, 0, 0);
        acc = __builtin_amdgcn_mfma_f32_16x16x32_bf16(afr[1], B[4], acc, 0, 0, 0);
        acc = __builtin_amdgcn_mfma_f32_16x16x32_bf16(afr[2], B[8], acc, 0, 0, 0);
        acc = __builtin_amdgcn_mfma_f32_16x16x32_bf16(afr[3], B[12], acc, 0, 0, 0);
        int colo = nt * 16 + r16;
#pragma unroll
        for (int r = 0; r < 4; ++r) {
            int row = kg * 4 + r;
            if (row < 8) {
                int ro = n0 + row;
                if (ro < N) Y[(size_t)ro * 128 + colo] = (unsigned short)f2bf(acc[r] * dv[r]);
            }
        }
    }
}

// AGG layer 2: Out = relu( dinv*( sum ew*H'[s] + H'[d] ) + b2 ), bf16 in/out
__global__ __launch_bounds__(256) void k_agg(const uint2* __restrict__ Hb2,
                                             const int* __restrict__ rowptr,
                                             const int2* __restrict__ cvb,
                                             const float* __restrict__ dinv,
                                             const float* __restrict__ bias,
                                             uint2* __restrict__ OutB2, int N) {
    __shared__ int2 lcv[4][4][2][64];  // 16 KB
    int tid = threadIdx.x;
    int lane = tid & 63, wid = tid >> 6;
    int half = lane >> 5, sl = lane & 31;
    int n0 = (blockIdx.x * 4 + wid) * 8;
    if (n0 >= N) return;
    int rv = rowptr[min(n0 + min(lane, 8), N)];
    int rp[9];
#pragma unroll
    for (int k = 0; k < 9; ++k) rp[k] = __shfl(rv, k);
    int cnt[8];
    int nmax = 0;
#pragma unroll
    for (int k = 0; k < 8; ++k) {
        cnt[k] = rp[k + 1] - rp[k];
        nmax = max(nmax, cnt[k]);
    }
    float a[4][4];
#pragma unroll
    for (int s = 0; s < 4; ++s) {
        int ns = n0 + 2 * s + half;
        uint2 hv = (ns < N) ? Hb2[(size_t)ns * 32 + sl] : make_uint2(0u, 0u);
        a[s][0] = bf_lo(hv.x);
        a[s][1] = bf_hi(hv.x);
        a[s][2] = bf_lo(hv.y);
        a[s][3] = bf_hi(hv.y);
    }
    for (int base = 0; base < nmax; base += 64) {
#pragma unroll
        for (int s = 0; s < 4; ++s) {
#pragma unroll
            for (int h = 0; h < 2; ++h) {
                int k = 2 * s + h;
                int2 t = (base + lane < cnt[k]) ? cvb[rp[k] + base + lane]
                                                : make_int2(0, 0);
                lcv[wid][s][h][lane] = t;
            }
        }
        int m = min(64, nmax - base);
        for (int j0 = 0; j0 < m; j0 += 8) {
#pragma unroll
            for (int jj = 0; jj < 8; ++jj) {
                int j = j0 + jj;
                if (j < m) {
                    int2 e0 = lcv[wid][0][half][j];
                    int2 e1 = lcv[wid][1][half][j];
                    int2 e2 = lcv[wid][2][half][j];
                    int2 e3 = lcv[wid][3][half][j];
                    uint2 h0 = Hb2[(size_t)e0.x * 32 + sl];
                    uint2 h1 = Hb2[(size_t)e1.x * 32 + sl];
                    uint2 h2 = Hb2[(size_t)e2.x * 32 + sl];
                    uint2 h3 = Hb2[(size_t)e3.x * 32 + sl];
                    float w0 = __int_as_float(e0.y);
                    float w1 = __int_as_float(e1.y);
                    float w2 = __int_as_float(e2.y);
                    float w3 = __int_as_float(e3.y);
                    a[0][0] = fmaf(w0, bf_lo(h0.x), a[0][0]);
                    a[0][1] = fmaf(w0, bf_hi(h0.x), a[0][1]);
                    a[0][2] = fmaf(w0, bf_lo(h0.y), a[0][2]);
                    a[0][3] = fmaf(w0, bf_hi(h0.y), a[0][3]);
                    a[1][0] = fmaf(w1, bf_lo(h1.x), a[1][0]);
                    a[1][1] = fmaf(w1, bf_hi(h1.x), a[1][1]);
                    a[1][2] = fmaf(w1, bf_lo(h1.y), a[1][2]);
                    a[1][3] = fmaf(w1, bf_hi(h1.y), a[1][3]);
                    a[2][0] = fmaf(w2, bf_lo(h2.x), a[2][0]);
                    a[2][1] = fmaf(w2, bf_hi(h2.x), a[2][1]);
                    a[2][2] = fmaf(w2, bf_lo(h2.y), a[2][2]);
                    a[2][3] = fmaf(w2, bf_hi(h2.y), a[2][3]);
                    a[3][0] = fmaf(w3, bf_lo(h3.x), a[3][0]);
                    a[3][1] = fmaf(w3, bf_hi(h3.x), a[3][1]);
                    a[3][2] = fmaf(w3, bf_lo(h3.y), a[3][2]);
                    a[3][3] = fmaf(w3, bf_hi(h3.y), a[3][3]);
                }
            }
        }
    }
    float4 bv = reinterpret_cast<const float4*>(bias)[sl];
#pragma unroll
    for (int s = 0; s < 4; ++s) {
        int ns = n0 + 2 * s + half;
        if (ns < N) {
            float d = dinv[ns];
            float o0 = fmaxf(fmaf(a[s][0], d, bv.x), 0.f);
            float o1 = fmaxf(fmaf(a[s][1], d, bv.y), 0.f);
            float o2 = fmaxf(fmaf(a[s][2], d, bv.z), 0.f);
            float o3 = fmaxf(fmaf(a[s][3], d, bv.w), 0.f);
            OutB2[(size_t)ns * 32 + sl] = make_uint2(packbf2(o0, o1), packbf2(o2, o3));
        }
    }
}

// fused mean-pool + head: out[g] = [pooled, relu(md@Wm+bm)] @ Wf + bf
__global__ __launch_bounds__(256) void k_poolhead(const unsigned int* __restrict__ H2u,
                                                  const int* __restrict__ gstart,
                                                  const int* __restrict__ gend,
                                                  const float* __restrict__ meta,
                                                  const float* __restrict__ Wm,
                                                  const float* __restrict__ bm,
                                                  const float* __restrict__ Wf,
                                                  const float* __restrict__ bf,
                                                  float* __restrict__ out, int G) {
    int g = blockIdx.x;
    int tid = threadIdx.x;
    int cu = tid & 63, q = tid >> 6;
    __shared__ float r0[256], r1[256];
    __shared__ float pooled[128];
    __shared__ float red[128];
    int b = gstart[g];
    int e = gend[g];
    int cntg = e - b;  // <=0 for empty graph (gstart=INT_MAX, gend=0)
    float s0 = 0.f, s1 = 0.f;
    for (int i = q; i < cntg; i += 4) {
        unsigned int v = H2u[(size_t)(b + i) * 64 + cu];
        s0 += bf_lo(v);
        s1 += bf_hi(v);
    }
    r0[tid] = s0; r1[tid] = s1;
    __syncthreads();
    if (tid < 64) {
        float t0 = r0[cu] + r0[cu + 64] + r0[cu + 128] + r0[cu + 192];
        float t1 = r1[cu] + r1[cu + 64] + r1[cu + 128] + r1[cu + 192];
        float inv = 1.f / fmaxf((float)cntg, 1.f);
        pooled[2 * cu] = t0 * inv;
        pooled[2 * cu + 1] = t1 * inv;
    }
    __syncthreads();
    if (tid < 128) {
        int c = tid;
        int idx = gstart[g] % G;  // INT_MAX for empty graph (segment_min identity)
        float m = bm[c];
#pragma unroll
        for (int k = 0; k < 30; ++k) m = fmaf(meta[idx * 30 + k], Wm[k * 128 + c], m);
        m = fmaxf(m, 0.f);
        red[c] = pooled[c] * Wf[c] + m * Wf[128 + c];
    }
    __syncthreads();
    for (int st = 64; st > 0; st >>= 1) {
        if (tid < st) red[tid] += red[tid + st];
        __syncthreads();
    }
    if (tid == 0) out[g] = red[0] + bf[0];
}

extern "C" void kernel_launch(void* const* d_in, const int* in_sizes, int n_in,
                              void* d_out, int out_size, void* d_ws, size_t ws_size,
                              hipStream_t stream) {
    const float* x     = (const float*)d_in[0];
    const int*   ei    = (const int*)d_in[1];
    const float* ew    = (const float*)d_in[2];
    const int*   batch = (const int*)d_in[3];
    const float* meta  = (const float*)d_in[4];
    const float* W1    = (const float*)d_in[5];
    const float* b1    = (const float*)d_in[6];
    const float* W2    = (const float*)d_in[7];
    const float* b2    = (const float*)d_in[8];
    const float* Wm    = (const float*)d_in[9];
    const float* bm    = (const float*)d_in[10];
    const float* Wf    = (const float*)d_in[11];
    const float* bf    = (const float*)d_in[12];

    int N = in_sizes[0] / 128;
    int E = in_sizes[2];
    int G = in_sizes[4] / 30;
    int Mpad = (N + 63) & ~63;
    int NBK = (N + BK_NODES - 1) >> BK_SHIFT;  // 196 for N=100000 (<=256)
    const int* srcp = ei;
    const int* dstp = ei + E;

    char* p = (char*)d_ws;
    auto alloc = [&](size_t bytes) -> void* {
        void* r = p;
        p += (bytes + 255) & ~(size_t)255;
        return r;
    };
    float* dinv   = (float*)alloc((size_t)N * 4);
    int*   rowptr = (int*)alloc((size_t)(N + 1) * 4);
    int2*  binned = (int2*)alloc((size_t)E * 8);
    int2*  cvb    = (int2*)alloc((size_t)E * 8);
    int*   bcnt   = (int*)alloc((size_t)NBK * 4);
    int*   bbase  = (int*)alloc((size_t)(NBK + 1) * 4);
    int*   bfillp = (int*)alloc((size_t)NBK * 4);
    unsigned short* H   = (unsigned short*)alloc((size_t)Mpad * 128 * 2);
    unsigned short* H2  = (unsigned short*)alloc((size_t)Mpad * 128 * 2);
    unsigned short* WT1 = (unsigned short*)alloc(128 * 128 * 2);
    unsigned short* WT2 = (unsigned short*)alloc(128 * 128 * 2);
    int*   gstart = (int*)alloc((size_t)G * 4);
    int*   gend   = (int*)alloc((size_t)G * 4);

    int EB = (E + CH - 1) / CH;
    k_init_small<<<(max(G, NBK) + 255) / 256, 256, 0, stream>>>(gstart, gend, G, bcnt, NBK);
    k_init_nodes<<<(N + 255) / 256, 256, 0, stream>>>(batch, gstart, gend, N);
    k_binhist<<<EB, 256, 0, stream>>>(dstp, E, bcnt, NBK);
    k_binscan<<<1, 256, 0, stream>>>(bcnt, bbase, bfillp, NBK);
    k_binscatter<<<EB, 256, 0, stream>>>(srcp, dstp, ew, bfillp, binned, E);
    k_csr<<<NBK, 256, 0, stream>>>(binned, bbase, cvb, rowptr, dinv, N, E);

    k_wtboth<<<128, 256, 0, stream>>>(W1, W2, WT1, WT2);

    k_gemm1<<<Mpad / 64, 256, 0, stream>>>(x, WT1, dinv, H, N);
    int NB32 = (N + 31) / 32;
    k_aggemm<<<NB32, 256, 0, stream>>>((const uint2*)H, rowptr, cvb, dinv, b1, WT2,
                                       H2, N);
    k_agg<<<NB32, 256, 0, stream>>>((const uint2*)H2, rowptr, cvb, dinv, b2,
                                    (uint2*)H, N);

    k_poolhead<<<G, 256, 0, stream>>>((const unsigned int*)H, gstart, gend,
                                      meta, Wm, bm, Wf, bf, (float*)d_out, G);
}

// Round 14
// 289.567 us; speedup vs baseline: 1.0844x; 1.0844x over previous
//
#include <hip/hip_runtime.h>
#include <cstdint>

// ---------------------------------------------------------------------------
// GCN pipeline (bf16 MFMA GEMMs, binned CSR build):
//  binhist(4-way) -> binscan -> binscatter -> k_csr(+fused W transposes) ->
//  GEMM1(fused cast, xW*dinv) -> AGGEMM (agg layer1 + block-fused GEMM2) ->
//  AGG2 -> fused pool+head.  Graph ranges via sorted-batch boundaries.
// ---------------------------------------------------------------------------

#define BK_SHIFT 9
#define BK_NODES 512            // 1 << BK_SHIFT
#define CH 4096                 // edges per binscatter chunk
#define NODE_BITS 17            // N=100000 < 2^17
#define NODE_MASK ((1 << NODE_BITS) - 1)

typedef short bf16x8 __attribute__((ext_vector_type(8)));
typedef float f32x4 __attribute__((ext_vector_type(4)));

union bfpack {
    uint4 u;
    bf16x8 b;
};

// f32 -> bf16 round-to-nearest-even
static __device__ __forceinline__ unsigned int f2bf(float f) {
    unsigned int u = __float_as_uint(f);
    return (u + 0x7fffu + ((u >> 16) & 1u)) >> 16;
}
static __device__ __forceinline__ unsigned int packbf2(float a, float b) {
    return f2bf(a) | (f2bf(b) << 16);
}
static __device__ __forceinline__ float bf_lo(unsigned int v) {
    return __uint_as_float(v << 16);
}
static __device__ __forceinline__ float bf_hi(unsigned int v) {
    return __uint_as_float(v & 0xffff0000u);
}

// gstart/gend init + zero bucket counters
__global__ void k_init_small(int* gstart, int* gend, int G, int* bcnt, int NBK) {
    int g = blockIdx.x * blockDim.x + threadIdx.x;
    if (g < G) { gstart[g] = 0x7fffffff; gend[g] = 0; }
    if (g < NBK) bcnt[g] = 0;
}

// sorted batch -> contiguous runs; boundary threads are unique writers
__global__ void k_init_nodes(const int* __restrict__ batch,
                             int* __restrict__ gstart, int* __restrict__ gend, int N) {
    int i = blockIdx.x * blockDim.x + threadIdx.x;
    if (i >= N) return;
    int b = batch[i];
    if (i == 0 || batch[i - 1] != b) gstart[b] = i;
    if (i == N - 1 || batch[i + 1] != b) gend[b] = i + 1;
}

// ---- Pass A1: per-bucket edge counts (4-way split hist: less contention) ---
__global__ __launch_bounds__(256) void k_binhist(const int* __restrict__ dst, int E,
                                                 int* __restrict__ bcnt, int NBK) {
    __shared__ int h[4][256];
    int tid = threadIdx.x;
    int wid = tid >> 6;
#pragma unroll
    for (int w = 0; w < 4; ++w) h[w][tid & 255] = 0;
    __syncthreads();
    int base = blockIdx.x * CH;
    int nend = min(base + CH, E);
    for (int i = base + tid; i < nend; i += 256) atomicAdd(&h[wid][dst[i] >> BK_SHIFT], 1);
    __syncthreads();
    if (tid < NBK) {
        int s = h[0][tid] + h[1][tid] + h[2][tid] + h[3][tid];
        if (s) atomicAdd(&bcnt[tid], s);
    }
}

// ---- Pass A2: scan bucket counts -> bbase[NBK+1], bfill cursors ------------
__global__ __launch_bounds__(256) void k_binscan(const int* __restrict__ bcnt,
                                                 int* __restrict__ bbase,
                                                 int* __restrict__ bfill, int NBK) {
    __shared__ int sc[256];
    int tid = threadIdx.x;
    int v = (tid < NBK) ? bcnt[tid] : 0;
    sc[tid] = v;
    __syncthreads();
    for (int d = 1; d < 256; d <<= 1) {
        int t = (tid >= d) ? sc[tid - d] : 0;
        __syncthreads();
        sc[tid] += t;
        __syncthreads();
    }
    int excl = sc[tid] - v;
    if (tid < NBK) { bbase[tid] = excl; bfill[tid] = excl; }
    if (tid == 255) bbase[NBK] = sc[255];  // total = E
}

// ---- Pass A3: counting-sort each 4096-edge chunk into bucket-major order ---
__global__ __launch_bounds__(256) void k_binscatter(const int* __restrict__ src,
                                                    const int* __restrict__ dst,
                                                    const float* __restrict__ ew,
                                                    int* __restrict__ bfill,
                                                    int2* __restrict__ binned, int E) {
    __shared__ int2 stage2[CH];          // 32 KB
    __shared__ unsigned char bkt2[CH];   // 4 KB
    __shared__ int hist[256], sc[256], lofs[256], cnt2[256], gbase[256];
    int tid = threadIdx.x;
    int base = blockIdx.x * CH;
    int n = min(CH, E - base);
    hist[tid] = 0;
    cnt2[tid] = 0;
    __syncthreads();
    int2 ev[CH / 256];
    int bk[CH / 256];
#pragma unroll
    for (int j = 0; j < CH / 256; ++j) {
        int i = base + tid + j * 256;
        bk[j] = -1;
        if (i < base + n) {
            int s = src[i], d = dst[i];
            float w = ew[i];
            int b = d >> BK_SHIFT;
            ev[j] = make_int2(s | ((d & (BK_NODES - 1)) << NODE_BITS), __float_as_int(w));
            bk[j] = b;
            atomicAdd(&hist[b], 1);
        }
    }
    __syncthreads();
    int hv = hist[tid];
    sc[tid] = hv;
    __syncthreads();
    for (int d = 1; d < 256; d <<= 1) {
        int t = (tid >= d) ? sc[tid - d] : 0;
        __syncthreads();
        sc[tid] += t;
        __syncthreads();
    }
    lofs[tid] = sc[tid] - hv;
    gbase[tid] = hv ? atomicAdd(&bfill[tid], hv) : 0;
    __syncthreads();
#pragma unroll
    for (int j = 0; j < CH / 256; ++j) {
        if (bk[j] >= 0) {
            int r = atomicAdd(&cnt2[bk[j]], 1);
            int p = lofs[bk[j]] + r;
            stage2[p] = ev[j];
            bkt2[p] = (unsigned char)bk[j];
        }
    }
    __syncthreads();
    for (int i = tid; i < n; i += 256) {
        int b = bkt2[i];
        binned[gbase[b] + (i - lofs[b])] = stage2[i];
    }
}

// ---- Pass B: per-bucket local CSR + rowptr + dinv; blocks >= NBK do the
//      W->WT bf16 transposes (independent work, saves a launch) -------------
__global__ __launch_bounds__(256) void k_csr(const int2* __restrict__ binned,
                                             const int* __restrict__ bbase,
                                             int2* __restrict__ cvb,
                                             int* __restrict__ rowptr,
                                             float* __restrict__ dinv, int N, int E,
                                             int NBK,
                                             const float* __restrict__ W1,
                                             const float* __restrict__ W2,
                                             unsigned short* __restrict__ WT1,
                                             unsigned short* __restrict__ WT2) {
    int tid = threadIdx.x;
    int b = blockIdx.x;
    if (b >= NBK) {
        int idx = (b - NBK) * 256 + tid;  // 128 blocks cover 32768 entries
        const float* W = (idx < 16384) ? W1 : W2;
        unsigned short* WT = (idx < 16384) ? WT1 : WT2;
        int i = idx & 16383;
        int n = i >> 7, k = i & 127;
        WT[i] = (unsigned short)f2bf(W[(size_t)k * 128 + n]);
        return;
    }
    __shared__ int lh[BK_NODES];
    __shared__ float ls[BK_NODES];
    __shared__ int lofs[BK_NODES];
    __shared__ int s2[256];
    int nbase = b << BK_SHIFT;
    int nend = min(nbase + BK_NODES, N);
    int ebase = bbase[b], eend = bbase[b + 1];
    for (int i = tid; i < BK_NODES; i += 256) { lh[i] = 0; ls[i] = 0.f; }
    __syncthreads();
    for (int e = ebase + tid; e < eend; e += 256) {
        int2 v = binned[e];
        int local = (v.x >> NODE_BITS) & (BK_NODES - 1);
        atomicAdd(&lh[local], 1);
        atomicAdd(&ls[local], __int_as_float(v.y));
    }
    __syncthreads();
    // exclusive scan of lh[512] via pairwise + 256-scan
    int p0 = lh[2 * tid], p1 = lh[2 * tid + 1];
    int pv = p0 + p1;
    s2[tid] = pv;
    __syncthreads();
    for (int d = 1; d < 256; d <<= 1) {
        int t = (tid >= d) ? s2[tid - d] : 0;
        __syncthreads();
        s2[tid] += t;
        __syncthreads();
    }
    int e2 = s2[tid] - pv;  // exclusive over pairs
    lofs[2 * tid] = e2;
    lofs[2 * tid + 1] = e2 + p0;
    __syncthreads();
    for (int i = nbase + tid; i < nend; i += 256) {
        int local = i - nbase;
        rowptr[i] = ebase + lofs[local];
        dinv[i] = rsqrtf(1.0f + ls[local]);
    }
    if (b == 0 && tid == 0) rowptr[N] = E;
    __syncthreads();
    for (int e = ebase + tid; e < eend; e += 256) {
        int2 v = binned[e];
        int local = (v.x >> NODE_BITS) & (BK_NODES - 1);
        int r = atomicAdd(&lofs[local], 1);
        cvb[ebase + r] = make_int2(v.x & NODE_MASK, v.y);
    }
}

// Layer 1: Y[M,128](bf16) = dinv[row] * (x_f32[M,128] @ W), cast fused.
__global__ __launch_bounds__(256) void k_gemm1(const float* __restrict__ X,
                                               const unsigned short* __restrict__ WT,
                                               const float* __restrict__ dinv,
                                               unsigned short* __restrict__ Y, int M) {
    int tid = threadIdx.x;
    int wid = tid >> 6, lane = tid & 63;
    int rowb = blockIdx.x * 64 + wid * 16;
    int r16 = lane & 15, kg = lane >> 4;
    int arow = min(rowb + r16, M - 1);  // clamp: garbage only affects unsaved pad rows
    const float* xr = X + (size_t)arow * 128 + kg * 8;
    bf16x8 a[4];
#pragma unroll
    for (int kc = 0; kc < 4; ++kc) {
        float4 u = *reinterpret_cast<const float4*>(xr + kc * 32);
        float4 v = *reinterpret_cast<const float4*>(xr + kc * 32 + 4);
        bfpack pk;
        pk.u = make_uint4(packbf2(u.x, u.y), packbf2(u.z, u.w),
                          packbf2(v.x, v.y), packbf2(v.z, v.w));
        a[kc] = pk.b;
    }
    float dv[4];
#pragma unroll
    for (int r = 0; r < 4; ++r) {
        int ro = rowb + kg * 4 + r;
        dv[r] = (ro < M) ? dinv[ro] : 0.f;
    }
    const bf16x8* Bp = reinterpret_cast<const bf16x8*>(WT + (size_t)r16 * 128 + kg * 8);
#pragma unroll
    for (int nt = 0; nt < 8; ++nt) {
        const bf16x8* B = Bp + (size_t)nt * 256;
        f32x4 acc = {0.f, 0.f, 0.f, 0.f};
        acc = __builtin_amdgcn_mfma_f32_16x16x32_bf16(a[0], B[0], acc, 0, 0, 0);
        acc = __builtin_amdgcn_mfma_f32_16x16x32_bf16(a[1], B[4], acc, 0, 0, 0);
        acc = __builtin_amdgcn_mfma_f32_16x16x32_bf16(a[2], B[8], acc, 0, 0, 0);
        acc = __builtin_amdgcn_mfma_f32_16x16x32_bf16(a[3], B[12], acc, 0, 0, 0);
        int colo = nt * 16 + r16;
#pragma unroll
        for (int r = 0; r < 4; ++r) {
            int ro = rowb + kg * 4 + r;
            if (ro < M) Y[(size_t)ro * 128 + colo] = (unsigned short)f2bf(acc[r] * dv[r]);
        }
    }
}

// AGG layer1 + fused GEMM2 (R12 barrier version — best measured).
// Gather phase (8 nodes/wave, half-wave rows) computes relu(dinv*agg + b1)
// rows; stage 32 rows/block in LDS; MFMA phase computes dinv * (rows @ W2).
__global__ __launch_bounds__(256) void k_aggemm(const uint2* __restrict__ Hb2,
                                                const int* __restrict__ rowptr,
                                                const int2* __restrict__ cvb,
                                                const float* __restrict__ dinv,
                                                const float* __restrict__ bias,
                                                const unsigned short* __restrict__ WT2,
                                                unsigned short* __restrict__ Y, int N) {
    __shared__ int2 lcv[4][4][2][64];  // 16 KB gather staging
    __shared__ uint2 hst[32][33];      // 8.25 KB relu'd rows (padded stride)
    int tid = threadIdx.x;
    int lane = tid & 63, wid = tid >> 6;
    int half = lane >> 5, sl = lane & 31;
    int blockbase = blockIdx.x * 32;
    int n0 = blockbase + wid * 8;
    bool active = (n0 < N);
    float a[4][4];
#pragma unroll
    for (int s = 0; s < 4; ++s)
#pragma unroll
        for (int q = 0; q < 4; ++q) a[s][q] = 0.f;
    if (active) {
        int rv = rowptr[min(n0 + min(lane, 8), N)];
        int rp[9];
#pragma unroll
        for (int k = 0; k < 9; ++k) rp[k] = __shfl(rv, k);
        int cnt[8];
        int nmax = 0;
#pragma unroll
        for (int k = 0; k < 8; ++k) {
            cnt[k] = rp[k + 1] - rp[k];
            nmax = max(nmax, cnt[k]);
        }
#pragma unroll
        for (int s = 0; s < 4; ++s) {
            int ns = n0 + 2 * s + half;
            uint2 hv = (ns < N) ? Hb2[(size_t)ns * 32 + sl] : make_uint2(0u, 0u);
            a[s][0] = bf_lo(hv.x);
            a[s][1] = bf_hi(hv.x);
            a[s][2] = bf_lo(hv.y);
            a[s][3] = bf_hi(hv.y);
        }
        for (int base = 0; base < nmax; base += 64) {
#pragma unroll
            for (int s = 0; s < 4; ++s) {
#pragma unroll
                for (int h = 0; h < 2; ++h) {
                    int k = 2 * s + h;
                    int2 t = (base + lane < cnt[k]) ? cvb[rp[k] + base + lane]
                                                    : make_int2(0, 0);
                    lcv[wid][s][h][lane] = t;
                }
            }
            int m = min(64, nmax - base);
            for (int j0 = 0; j0 < m; j0 += 8) {
#pragma unroll
                for (int jj = 0; jj < 8; ++jj) {
                    int j = j0 + jj;
                    if (j < m) {
                        int2 e0 = lcv[wid][0][half][j];
                        int2 e1 = lcv[wid][1][half][j];
                        int2 e2 = lcv[wid][2][half][j];
                        int2 e3 = lcv[wid][3][half][j];
                        uint2 h0 = Hb2[(size_t)e0.x * 32 + sl];
                        uint2 h1 = Hb2[(size_t)e1.x * 32 + sl];
                        uint2 h2 = Hb2[(size_t)e2.x * 32 + sl];
                        uint2 h3 = Hb2[(size_t)e3.x * 32 + sl];
                        float w0 = __int_as_float(e0.y);
                        float w1 = __int_as_float(e1.y);
                        float w2 = __int_as_float(e2.y);
                        float w3 = __int_as_float(e3.y);
                        a[0][0] = fmaf(w0, bf_lo(h0.x), a[0][0]);
                        a[0][1] = fmaf(w0, bf_hi(h0.x), a[0][1]);
                        a[0][2] = fmaf(w0, bf_lo(h0.y), a[0][2]);
                        a[0][3] = fmaf(w0, bf_hi(h0.y), a[0][3]);
                        a[1][0] = fmaf(w1, bf_lo(h1.x), a[1][0]);
                        a[1][1] = fmaf(w1, bf_hi(h1.x), a[1][1]);
                        a[1][2] = fmaf(w1, bf_lo(h1.y), a[1][2]);
                        a[1][3] = fmaf(w1, bf_hi(h1.y), a[1][3]);
                        a[2][0] = fmaf(w2, bf_lo(h2.x), a[2][0]);
                        a[2][1] = fmaf(w2, bf_hi(h2.x), a[2][1]);
                        a[2][2] = fmaf(w2, bf_lo(h2.y), a[2][2]);
                        a[2][3] = fmaf(w2, bf_hi(h2.y), a[2][3]);
                        a[3][0] = fmaf(w3, bf_lo(h3.x), a[3][0]);
                        a[3][1] = fmaf(w3, bf_hi(h3.x), a[3][1]);
                        a[3][2] = fmaf(w3, bf_lo(h3.y), a[3][2]);
                        a[3][3] = fmaf(w3, bf_hi(h3.y), a[3][3]);
                    }
                }
            }
        }
    }
    // bias + relu -> stage rows into LDS (pad rows = 0)
    float4 bv = reinterpret_cast<const float4*>(bias)[sl];
#pragma unroll
    for (int s = 0; s < 4; ++s) {
        int ns = n0 + 2 * s + half;
        uint2 o = make_uint2(0u, 0u);
        if (active && ns < N) {
            float d = dinv[ns];
            float o0 = fmaxf(fmaf(a[s][0], d, bv.x), 0.f);
            float o1 = fmaxf(fmaf(a[s][1], d, bv.y), 0.f);
            float o2 = fmaxf(fmaf(a[s][2], d, bv.z), 0.f);
            float o3 = fmaxf(fmaf(a[s][3], d, bv.w), 0.f);
            o = make_uint2(packbf2(o0, o1), packbf2(o2, o3));
        }
        hst[wid * 8 + 2 * s + half][sl] = o;
    }
    __syncthreads();
    // ---- MFMA phase: 32x128 @ 128x128; wave -> 16-row x 64-col tile ----
    int r16 = lane & 15, kg = lane >> 4;
    int trow = wid >> 1;
    int ntb = (wid & 1) * 4;
    int arow = trow * 16 + r16;
    bf16x8 afr[4];
#pragma unroll
    for (int kc = 0; kc < 4; ++kc) {
        uint2 lo = hst[arow][kc * 8 + kg * 2];
        uint2 hi = hst[arow][kc * 8 + kg * 2 + 1];
        bfpack pk;
        pk.u = make_uint4(lo.x, lo.y, hi.x, hi.y);
        afr[kc] = pk.b;
    }
    float dv[4];
#pragma unroll
    for (int r = 0; r < 4; ++r) {
        int ro = blockbase + trow * 16 + kg * 4 + r;
        dv[r] = (ro < N) ? dinv[ro] : 0.f;
    }
    const bf16x8* Bp = reinterpret_cast<const bf16x8*>(WT2 + (size_t)r16 * 128 + kg * 8);
#pragma unroll
    for (int nt = 0; nt < 4; ++nt) {
        const bf16x8* B = Bp + (size_t)(ntb + nt) * 256;
        f32x4 acc = {0.f, 0.f, 0.f, 0.f};
        acc = __builtin_amdgcn_mfma_f32_16x16x32_bf16(afr[0], B[0], acc, 0, 0, 0);
        acc = __builtin_amdgcn_mfma_f32_16x16x32_bf16(afr[1], B[4], acc, 0, 0, 0);
        acc = __builtin_amdgcn_mfma_f32_16x16x32_bf16(afr[2], B[8], acc, 0, 0, 0);
        acc = __builtin_amdgcn_mfma_f32_16x16x32_bf16(afr[3], B[12], acc, 0, 0, 0);
        int colo = (ntb + nt) * 16 + r16;
#pragma unroll
        for (int r = 0; r < 4; ++r) {
            int ro = blockbase + trow * 16 + kg * 4 + r;
            if (ro < N) Y[(size_t)ro * 128 + colo] = (unsigned short)f2bf(acc[r] * dv[r]);
        }
    }
}

// AGG layer 2: Out = relu( dinv*( sum ew*H'[s] + H'[d] ) + b2 ), bf16 in/out
__global__ __launch_bounds__(256) void k_agg(const uint2* __restrict__ Hb2,
                                             const int* __restrict__ rowptr,
                                             const int2* __restrict__ cvb,
                                             const float* __restrict__ dinv,
                                             const float* __restrict__ bias,
                                             uint2* __restrict__ OutB2, int N) {
    __shared__ int2 lcv[4][4][2][64];  // 16 KB
    int tid = threadIdx.x;
    int lane = tid & 63, wid = tid >> 6;
    int half = lane >> 5, sl = lane & 31;
    int n0 = (blockIdx.x * 4 + wid) * 8;
    if (n0 >= N) return;
    int rv = rowptr[min(n0 + min(lane, 8), N)];
    int rp[9];
#pragma unroll
    for (int k = 0; k < 9; ++k) rp[k] = __shfl(rv, k);
    int cnt[8];
    int nmax = 0;
#pragma unroll
    for (int k = 0; k < 8; ++k) {
        cnt[k] = rp[k + 1] - rp[k];
        nmax = max(nmax, cnt[k]);
    }
    float a[4][4];
#pragma unroll
    for (int s = 0; s < 4; ++s) {
        int ns = n0 + 2 * s + half;
        uint2 hv = (ns < N) ? Hb2[(size_t)ns * 32 + sl] : make_uint2(0u, 0u);
        a[s][0] = bf_lo(hv.x);
        a[s][1] = bf_hi(hv.x);
        a[s][2] = bf_lo(hv.y);
        a[s][3] = bf_hi(hv.y);
    }
    for (int base = 0; base < nmax; base += 64) {
#pragma unroll
        for (int s = 0; s < 4; ++s) {
#pragma unroll
            for (int h = 0; h < 2; ++h) {
                int k = 2 * s + h;
                int2 t = (base + lane < cnt[k]) ? cvb[rp[k] + base + lane]
                                                : make_int2(0, 0);
                lcv[wid][s][h][lane] = t;
            }
        }
        int m = min(64, nmax - base);
        for (int j0 = 0; j0 < m; j0 += 8) {
#pragma unroll
            for (int jj = 0; jj < 8; ++jj) {
                int j = j0 + jj;
                if (j < m) {
                    int2 e0 = lcv[wid][0][half][j];
                    int2 e1 = lcv[wid][1][half][j];
                    int2 e2 = lcv[wid][2][half][j];
                    int2 e3 = lcv[wid][3][half][j];
                    uint2 h0 = Hb2[(size_t)e0.x * 32 + sl];
                    uint2 h1 = Hb2[(size_t)e1.x * 32 + sl];
                    uint2 h2 = Hb2[(size_t)e2.x * 32 + sl];
                    uint2 h3 = Hb2[(size_t)e3.x * 32 + sl];
                    float w0 = __int_as_float(e0.y);
                    float w1 = __int_as_float(e1.y);
                    float w2 = __int_as_float(e2.y);
                    float w3 = __int_as_float(e3.y);
                    a[0][0] = fmaf(w0, bf_lo(h0.x), a[0][0]);
                    a[0][1] = fmaf(w0, bf_hi(h0.x), a[0][1]);
                    a[0][2] = fmaf(w0, bf_lo(h0.y), a[0][2]);
                    a[0][3] = fmaf(w0, bf_hi(h0.y), a[0][3]);
                    a[1][0] = fmaf(w1, bf_lo(h1.x), a[1][0]);
                    a[1][1] = fmaf(w1, bf_hi(h1.x), a[1][1]);
                    a[1][2] = fmaf(w1, bf_lo(h1.y), a[1][2]);
                    a[1][3] = fmaf(w1, bf_hi(h1.y), a[1][3]);
                    a[2][0] = fmaf(w2, bf_lo(h2.x), a[2][0]);
                    a[2][1] = fmaf(w2, bf_hi(h2.x), a[2][1]);
                    a[2][2] = fmaf(w2, bf_lo(h2.y), a[2][2]);
                    a[2][3] = fmaf(w2, bf_hi(h2.y), a[2][3]);
                    a[3][0] = fmaf(w3, bf_lo(h3.x), a[3][0]);
                    a[3][1] = fmaf(w3, bf_hi(h3.x), a[3][1]);
                    a[3][2] = fmaf(w3, bf_lo(h3.y), a[3][2]);
                    a[3][3] = fmaf(w3, bf_hi(h3.y), a[3][3]);
                }
            }
        }
    }
    float4 bv = reinterpret_cast<const float4*>(bias)[sl];
#pragma unroll
    for (int s = 0; s < 4; ++s) {
        int ns = n0 + 2 * s + half;
        if (ns < N) {
            float d = dinv[ns];
            float o0 = fmaxf(fmaf(a[s][0], d, bv.x), 0.f);
            float o1 = fmaxf(fmaf(a[s][1], d, bv.y), 0.f);
            float o2 = fmaxf(fmaf(a[s][2], d, bv.z), 0.f);
            float o3 = fmaxf(fmaf(a[s][3], d, bv.w), 0.f);
            OutB2[(size_t)ns * 32 + sl] = make_uint2(packbf2(o0, o1), packbf2(o2, o3));
        }
    }
}

// fused mean-pool + head: out[g] = [pooled, relu(md@Wm+bm)] @ Wf + bf
__global__ __launch_bounds__(256) void k_poolhead(const unsigned int* __restrict__ H2u,
                                                  const int* __restrict__ gstart,
                                                  const int* __restrict__ gend,
                                                  const float* __restrict__ meta,
                                                  const float* __restrict__ Wm,
                                                  const float* __restrict__ bm,
                                                  const float* __restrict__ Wf,
                                                  const float* __restrict__ bf,
                                                  float* __restrict__ out, int G) {
    int g = blockIdx.x;
    int tid = threadIdx.x;
    int cu = tid & 63, q = tid >> 6;
    __shared__ float r0[256], r1[256];
    __shared__ float pooled[128];
    __shared__ float red[128];
    int b = gstart[g];
    int e = gend[g];
    int cntg = e - b;  // <=0 for empty graph (gstart=INT_MAX, gend=0)
    float s0 = 0.f, s1 = 0.f;
    for (int i = q; i < cntg; i += 4) {
        unsigned int v = H2u[(size_t)(b + i) * 64 + cu];
        s0 += bf_lo(v);
        s1 += bf_hi(v);
    }
    r0[tid] = s0; r1[tid] = s1;
    __syncthreads();
    if (tid < 64) {
        float t0 = r0[cu] + r0[cu + 64] + r0[cu + 128] + r0[cu + 192];
        float t1 = r1[cu] + r1[cu + 64] + r1[cu + 128] + r1[cu + 192];
        float inv = 1.f / fmaxf((float)cntg, 1.f);
        pooled[2 * cu] = t0 * inv;
        pooled[2 * cu + 1] = t1 * inv;
    }
    __syncthreads();
    if (tid < 128) {
        int c = tid;
        int idx = gstart[g] % G;  // INT_MAX for empty graph (segment_min identity)
        float m = bm[c];
#pragma unroll
        for (int k = 0; k < 30; ++k) m = fmaf(meta[idx * 30 + k], Wm[k * 128 + c], m);
        m = fmaxf(m, 0.f);
        red[c] = pooled[c] * Wf[c] + m * Wf[128 + c];
    }
    __syncthreads();
    for (int st = 64; st > 0; st >>= 1) {
        if (tid < st) red[tid] += red[tid + st];
        __syncthreads();
    }
    if (tid == 0) out[g] = red[0] + bf[0];
}

extern "C" void kernel_launch(void* const* d_in, const int* in_sizes, int n_in,
                              void* d_out, int out_size, void* d_ws, size_t ws_size,
                              hipStream_t stream) {
    const float* x     = (const float*)d_in[0];
    const int*   ei    = (const int*)d_in[1];
    const float* ew    = (const float*)d_in[2];
    const int*   batch = (const int*)d_in[3];
    const float* meta  = (const float*)d_in[4];
    const float* W1    = (const float*)d_in[5];
    const float* b1    = (const float*)d_in[6];
    const float* W2    = (const float*)d_in[7];
    const float* b2    = (const float*)d_in[8];
    const float* Wm    = (const float*)d_in[9];
    const float* bm    = (const float*)d_in[10];
    const float* Wf    = (const float*)d_in[11];
    const float* bf    = (const float*)d_in[12];

    int N = in_sizes[0] / 128;
    int E = in_sizes[2];
    int G = in_sizes[4] / 30;
    int Mpad = (N + 63) & ~63;
    int NBK = (N + BK_NODES - 1) >> BK_SHIFT;  // 196 for N=100000 (<=256)
    const int* srcp = ei;
    const int* dstp = ei + E;

    char* p = (char*)d_ws;
    auto alloc = [&](size_t bytes) -> void* {
        void* r = p;
        p += (bytes + 255) & ~(size_t)255;
        return r;
    };
    float* dinv   = (float*)alloc((size_t)N * 4);
    int*   rowptr = (int*)alloc((size_t)(N + 1) * 4);
    int2*  binned = (int2*)alloc((size_t)E * 8);
    int2*  cvb    = (int2*)alloc((size_t)E * 8);
    int*   bcnt   = (int*)alloc((size_t)NBK * 4);
    int*   bbase  = (int*)alloc((size_t)(NBK + 1) * 4);
    int*   bfillp = (int*)alloc((size_t)NBK * 4);
    unsigned short* H   = (unsigned short*)alloc((size_t)Mpad * 128 * 2);
    unsigned short* H2  = (unsigned short*)alloc((size_t)Mpad * 128 * 2);
    unsigned short* WT1 = (unsigned short*)alloc(128 * 128 * 2);
    unsigned short* WT2 = (unsigned short*)alloc(128 * 128 * 2);
    int*   gstart = (int*)alloc((size_t)G * 4);
    int*   gend   = (int*)alloc((size_t)G * 4);

    int EB = (E + CH - 1) / CH;
    k_init_small<<<(max(G, NBK) + 255) / 256, 256, 0, stream>>>(gstart, gend, G, bcnt, NBK);
    k_init_nodes<<<(N + 255) / 256, 256, 0, stream>>>(batch, gstart, gend, N);
    k_binhist<<<EB, 256, 0, stream>>>(dstp, E, bcnt, NBK);
    k_binscan<<<1, 256, 0, stream>>>(bcnt, bbase, bfillp, NBK);
    k_binscatter<<<EB, 256, 0, stream>>>(srcp, dstp, ew, bfillp, binned, E);
    k_csr<<<NBK + 128, 256, 0, stream>>>(binned, bbase, cvb, rowptr, dinv, N, E,
                                         NBK, W1, W2, WT1, WT2);

    k_gemm1<<<Mpad / 64, 256, 0, stream>>>(x, WT1, dinv, H, N);
    int NB32 = (N + 31) / 32;
    k_aggemm<<<NB32, 256, 0, stream>>>((const uint2*)H, rowptr, cvb, dinv, b1, WT2,
                                       H2, N);
    k_agg<<<NB32, 256, 0, stream>>>((const uint2*)H2, rowptr, cvb, dinv, b2,
                                    (uint2*)H, N);

    k_poolhead<<<G, 256, 0, stream>>>((const unsigned int*)H, gstart, gend,
                                      meta, Wm, bm, Wf, bf, (float*)d_out, G);
}